// Round 1
// baseline (88.962 us; speedup 1.0000x reference)
//
#include <hip/hip_runtime.h>

// NSLayer: out = X + (-a*(X X^T) + b*(X X^T)^2) X  per (b,c) slice, X: [N=512, D=64]
// Factored through G = X^T X (64x64):  out = X + X*H,  H = -a*G + b*G^2 (symmetric).
// One block per slice (B*C = 512 blocks), 256 threads.

namespace {

constexpr int N_ROWS = 512;   // N
constexpr int DD     = 64;    // D
constexpr int CHUNK  = 64;    // rows staged per LDS chunk
constexpr int NCHUNK = N_ROWS / CHUNK;  // 8

// LDS float index for a [64][64] row-major tile with 16B-granule XOR swizzle.
// granule gr in [0,16); XOR the low 3 bits with (row>>2)&7 so that
// same-granule reads across 16 consecutive-row-quads hit 8 distinct bank
// groups (2-way conflict = free) instead of 8-way.
__device__ __forceinline__ int swz_idx(int row, int gr) {
    return (row << 6) + ((gr ^ ((row >> 2) & 7)) << 2);
}

__global__ __launch_bounds__(256) void ns_fused(const float* __restrict__ inp,
                                                const float* __restrict__ aw,
                                                const float* __restrict__ bw,
                                                float* __restrict__ out) {
    __shared__ float Xs[CHUNK * DD];  // 16 KiB
    __shared__ float Gs[DD * DD];     // 16 KiB
    __shared__ float Hs[DD * DD];     // 16 KiB

    const int slice = blockIdx.x;               // b*64 + c
    const float av = aw[slice & 63];
    const float bv = bw[slice & 63];
    const float* __restrict__ X = inp + (size_t)slice * (N_ROWS * DD);
    float* __restrict__ O       = out + (size_t)slice * (N_ROWS * DD);

    const int t  = threadIdx.x;
    const int ti = t >> 4;    // 0..15
    const int tj = t & 15;    // 0..15
    const int i0 = ti << 2;   // row base of this thread's 4x4 tile
    const int j0 = tj << 2;   // col base

    // ---------------- Pass 1: G = X^T X ----------------
    float g[4][4];
#pragma unroll
    for (int r = 0; r < 4; ++r)
#pragma unroll
        for (int c = 0; c < 4; ++c) g[r][c] = 0.f;

    for (int ch = 0; ch < NCHUNK; ++ch) {
        __syncthreads();  // protect Xs from previous-iteration readers
        {
            const float4* src = (const float4*)(X + ch * (CHUNK * DD));
#pragma unroll
            for (int gq = 0; gq < 4; ++gq) {
                const int f = t + 256 * gq;          // float4 index, 0..1023
                const float4 v = src[f];             // fully coalesced
                *(float4*)&Xs[swz_idx(f >> 4, f & 15)] = v;
            }
        }
        __syncthreads();
#pragma unroll 8
        for (int n = 0; n < CHUNK; ++n) {
            const float4 xi = *(const float4*)&Xs[swz_idx(n, ti)];
            const float4 xj = *(const float4*)&Xs[swz_idx(n, tj)];
            g[0][0] += xi.x * xj.x; g[0][1] += xi.x * xj.y; g[0][2] += xi.x * xj.z; g[0][3] += xi.x * xj.w;
            g[1][0] += xi.y * xj.x; g[1][1] += xi.y * xj.y; g[1][2] += xi.y * xj.z; g[1][3] += xi.y * xj.w;
            g[2][0] += xi.z * xj.x; g[2][1] += xi.z * xj.y; g[2][2] += xi.z * xj.z; g[2][3] += xi.z * xj.w;
            g[3][0] += xi.w * xj.x; g[3][1] += xi.w * xj.y; g[3][2] += xi.w * xj.z; g[3][3] += xi.w * xj.w;
        }
    }

    // Store G tile to LDS (rows i0..i0+3, cols j0..j0+3 => granule tj)
#pragma unroll
    for (int r = 0; r < 4; ++r) {
        const float4 v = make_float4(g[r][0], g[r][1], g[r][2], g[r][3]);
        *(float4*)&Gs[swz_idx(i0 + r, tj)] = v;
    }
    __syncthreads();

    // ---------------- Pass 2: H = -a*G + b*G^2 ----------------
    // G symmetric => (G^2)[i][j] = dot(G_row_i, G_row_j)
    float h[4][4];
#pragma unroll
    for (int r = 0; r < 4; ++r)
#pragma unroll
        for (int c = 0; c < 4; ++c) h[r][c] = 0.f;

#pragma unroll 4
    for (int kq = 0; kq < 16; ++kq) {
        float4 gi[4], gj[4];
#pragma unroll
        for (int r = 0; r < 4; ++r) gi[r] = *(const float4*)&Gs[swz_idx(i0 + r, kq)];
#pragma unroll
        for (int c = 0; c < 4; ++c) gj[c] = *(const float4*)&Gs[swz_idx(j0 + c, kq)];
#pragma unroll
        for (int r = 0; r < 4; ++r)
#pragma unroll
            for (int c = 0; c < 4; ++c)
                h[r][c] += gi[r].x * gj[c].x + gi[r].y * gj[c].y +
                           gi[r].z * gj[c].z + gi[r].w * gj[c].w;
    }
#pragma unroll
    for (int r = 0; r < 4; ++r) {
        const float4 gg = *(const float4*)&Gs[swz_idx(i0 + r, tj)];
        float4 hv;
        hv.x = bv * h[r][0] - av * gg.x;
        hv.y = bv * h[r][1] - av * gg.y;
        hv.z = bv * h[r][2] - av * gg.z;
        hv.w = bv * h[r][3] - av * gg.w;
        *(float4*)&Hs[swz_idx(i0 + r, tj)] = hv;
    }
    __syncthreads();

    // ---------------- Pass 3: out = X + X*H ----------------
    // H symmetric => H[k][d] = H[d][k]: read H rows d0+c as b128.
    for (int ch = 0; ch < NCHUNK; ++ch) {
        __syncthreads();  // protect Xs from previous-iteration readers
        {
            const float4* src = (const float4*)(X + ch * (CHUNK * DD));
#pragma unroll
            for (int gq = 0; gq < 4; ++gq) {
                const int f = t + 256 * gq;
                const float4 v = src[f];
                *(float4*)&Xs[swz_idx(f >> 4, f & 15)] = v;
            }
        }
        __syncthreads();

        float o[4][4];
#pragma unroll
        for (int r = 0; r < 4; ++r)
#pragma unroll
            for (int c = 0; c < 4; ++c) o[r][c] = 0.f;

#pragma unroll 4
        for (int kq = 0; kq < 16; ++kq) {
            float4 xr[4], hc[4];
#pragma unroll
            for (int r = 0; r < 4; ++r) xr[r] = *(const float4*)&Xs[swz_idx(i0 + r, kq)];
#pragma unroll
            for (int c = 0; c < 4; ++c) hc[c] = *(const float4*)&Hs[swz_idx(j0 + c, kq)];
#pragma unroll
            for (int r = 0; r < 4; ++r)
#pragma unroll
                for (int c = 0; c < 4; ++c)
                    o[r][c] += xr[r].x * hc[c].x + xr[r].y * hc[c].y +
                               xr[r].z * hc[c].z + xr[r].w * hc[c].w;
        }

        // epilogue: out = X + X*H, coalesced float4 stores
#pragma unroll
        for (int r = 0; r < 4; ++r) {
            const float4 xv = *(const float4*)&Xs[swz_idx(i0 + r, tj)];
            float4 ov;
            ov.x = xv.x + o[r][0];
            ov.y = xv.y + o[r][1];
            ov.z = xv.z + o[r][2];
            ov.w = xv.w + o[r][3];
            *(float4*)&O[(size_t)(ch * CHUNK + i0 + r) * DD + j0] = ov;
        }
    }
}

}  // namespace

extern "C" void kernel_launch(void* const* d_in, const int* in_sizes, int n_in,
                              void* d_out, int out_size, void* d_ws, size_t ws_size,
                              hipStream_t stream) {
    const float* inp = (const float*)d_in[0];
    const float* aw  = (const float*)d_in[1];
    const float* bw  = (const float*)d_in[2];
    float* out       = (float*)d_out;

    // B*C = 8*64 = 512 slices, one block each.
    ns_fused<<<dim3(512), dim3(256), 0, stream>>>(inp, aw, bw, out);
}

// Round 2
// 34.713 us; speedup vs baseline: 2.5627x; 2.5627x over previous
//
#include <hip/hip_runtime.h>

// NSLayer: out = X + (-a*(X X^T) + b*(X X^T)^2) X per (b,c) slice, X: [512][64].
// Factored: G = X^T X (64x64), H = -a*G + b*G^2 (symmetric), out = X + X*H.
// bf16 MFMA (32x32x16) for all three matmuls, fp32 accumulate.
// 512 blocks (1 slice each) x 512 threads (8 waves). LDS 61 KiB -> 2 blocks/CU.

typedef __bf16 bf16;
typedef __attribute__((ext_vector_type(8)))  __bf16 bf16x8;
typedef __attribute__((ext_vector_type(4)))  __bf16 bf16x4;
typedef __attribute__((ext_vector_type(16))) float  f32x16;

namespace {

constexpr int NROWS = 512;
constexpr int DD    = 64;

// LDS byte map (total 62464):
//   [0,18432):      pass1: Xt0[64][72]bf16 (9216) + Xt1[64][72]bf16
//                   pass3: Xr[128][72]bf16 (overlay)
//   [18432,53248):  pass1: Gp0[64][68]f32 (17408) + Gp1[64][68]f32
//                   pass2+: Gbf[64][72]bf16 (overlay of Gp0, written after reads)
//   [53248,62464):  Hbf[64][72]bf16

__device__ __forceinline__ int sxz(int d) { return ((d >> 1) ^ (d >> 4)) & 7; }

__global__ __launch_bounds__(512, 4)
void ns_mfma(const float* __restrict__ inp, const float* __restrict__ aw,
             const float* __restrict__ bw, float* __restrict__ out) {
    __shared__ unsigned char smem[62464] __attribute__((aligned(128)));
    bf16*  const Xt0 = (bf16*)smem;                      // [64][72]
    bf16*  const Xt1 = (bf16*)(smem + 9216);             // [64][72]
    bf16*  const Xr  = (bf16*)smem;                      // [128][72]
    float* const Gp0 = (float*)(smem + 18432);           // [64][68]
    float* const Gp1 = (float*)(smem + 18432 + 17408);   // [64][68]
    bf16*  const Gbf = (bf16*)(smem + 18432);            // [64][72]
    bf16*  const Hbf = (bf16*)(smem + 53248);            // [64][72]

    const int slice = blockIdx.x;                // b*64 + c
    const float av = aw[slice & 63];
    const float bv = bw[slice & 63];
    const float* __restrict__ X = inp + (size_t)slice * (NROWS * DD);
    float* __restrict__ O       = out + (size_t)slice * (NROWS * DD);

    const int t    = threadIdx.x;
    const int lane = t & 63;
    const int w    = t >> 6;       // wave 0..7
    const int l31  = lane & 31;
    const int l5   = lane >> 5;    // 0/1

    // ================= Pass 1: G = X^T X, K-split into 2 halves =============
    f32x16 acc;
#pragma unroll
    for (int q = 0; q < 16; ++q) acc[q] = 0.f;

    const int half = t >> 8;           // threads 0-255 -> half 0 (waves 0-3)
    const int th   = t & 255;
    const int s_nq = th >> 4;          // n-quad 0..15
    const int s_dq = th & 15;          // d-quad 0..15
    bf16* const XtMine = half ? Xt1 : Xt0;   // note: (w>>2)==half

    const int tile = w & 3;
    const int i32  = (tile >> 1) * 32;
    const int j32  = (tile & 1) * 32;
    const int rowA = i32 + l31;
    const int rowB = j32 + l31;
    const int sA   = sxz(rowA);
    const int sB   = sxz(rowB);

    for (int it = 0; it < 4; ++it) {
        // --- stage chunk (it + 4*half): transpose fp32 -> bf16 into XtMine ---
        {
            const int ch = it + 4 * half;
            float4 rv[4];
#pragma unroll
            for (int rn = 0; rn < 4; ++rn)
                rv[rn] = *(const float4*)&X[(ch * 64 + 4 * s_nq + rn) * DD + 4 * s_dq];
#pragma unroll
            for (int r = 0; r < 4; ++r) {
                const int d = 4 * s_dq + r;
                bf16x4 v;
#pragma unroll
                for (int rn = 0; rn < 4; ++rn) {
                    const float f = (r == 0) ? rv[rn].x : (r == 1) ? rv[rn].y
                                  : (r == 2) ? rv[rn].z : rv[rn].w;
                    v[rn] = (bf16)f;
                }
                const int g = ((s_nq >> 1) ^ sxz(d)) & 7;   // 16B-granule swizzle
                *(bf16x4*)&XtMine[d * 72 + g * 8 + 4 * (s_nq & 1)] = v;
            }
        }
        __syncthreads();
        // --- compute: 4 K-steps (K=16 each) on this 64-n chunk ---
#pragma unroll
        for (int ks = 0; ks < 4; ++ks) {
            const int gw = 2 * ks + l5;   // wanted granule (8 n each)
            bf16x8 a = *(const bf16x8*)&XtMine[rowA * 72 + ((gw ^ sA) & 7) * 8];
            bf16x8 b = *(const bf16x8*)&XtMine[rowB * 72 + ((gw ^ sB) & 7) * 8];
            acc = __builtin_amdgcn_mfma_f32_32x32x16_bf16(a, b, acc, 0, 0, 0);
        }
        __syncthreads();
    }

    // store partial G tiles
    {
        float* const Gp = half ? Gp1 : Gp0;
#pragma unroll
        for (int q = 0; q < 16; ++q) {
            const int r = (q & 3) + 8 * (q >> 2) + 4 * l5;   // C/D row (m74/m101)
            Gp[(i32 + r) * 68 + j32 + l31] = acc[q];
        }
    }
    __syncthreads();

    // ================= Combine: G = Gp0 + Gp1 -> Gbf (bf16) =================
    {
        const int ci = t >> 3;           // 0..63
        const int cj = (t & 7) * 8;      // 0..56
        const float4 a0 = *(const float4*)&Gp0[ci * 68 + cj];
        const float4 a1 = *(const float4*)&Gp0[ci * 68 + cj + 4];
        const float4 b0 = *(const float4*)&Gp1[ci * 68 + cj];
        const float4 b1 = *(const float4*)&Gp1[ci * 68 + cj + 4];
        float s[8];
        s[0] = a0.x + b0.x; s[1] = a0.y + b0.y; s[2] = a0.z + b0.z; s[3] = a0.w + b0.w;
        s[4] = a1.x + b1.x; s[5] = a1.y + b1.y; s[6] = a1.z + b1.z; s[7] = a1.w + b1.w;
        __syncthreads();                  // all Gp reads done before Gbf overlay write
        bf16x8 v;
#pragma unroll
        for (int q = 0; q < 8; ++q) v[q] = (bf16)s[q];
        *(bf16x8*)&Gbf[ci * 72 + cj] = v;
    }
    __syncthreads();

    // ================= Pass 2: H = b*G^2 - a*G (waves 0-3) ==================
    if (w < 4) {
        const int pi = (w >> 1) * 32;
        const int pj = (w & 1) * 32;
        f32x16 h;
#pragma unroll
        for (int q = 0; q < 16; ++q) h[q] = 0.f;
#pragma unroll
        for (int ks = 0; ks < 4; ++ks) {
            // G symmetric: both operands are row reads of Gbf
            bf16x8 a = *(const bf16x8*)&Gbf[(pi + l31) * 72 + ks * 16 + 8 * l5];
            bf16x8 b = *(const bf16x8*)&Gbf[(pj + l31) * 72 + ks * 16 + 8 * l5];
            h = __builtin_amdgcn_mfma_f32_32x32x16_bf16(a, b, h, 0, 0, 0);
        }
#pragma unroll
        for (int q = 0; q < 16; ++q) {
            const int r  = (q & 3) + 8 * (q >> 2) + 4 * l5;
            const int ii = pi + r;
            const int jj = pj + l31;
            Hbf[ii * 72 + jj] = (bf16)(bv * h[q] - av * (float)Gbf[ii * 72 + jj]);
        }
    }
    __syncthreads();

    // ================= Pass 3: out = X + X*H =================================
    const int p_nq = t >> 4;         // 0..31
    const int p_dq = t & 15;
    const int nb   = (w >> 1) * 32;  // n-block within 128-row chunk
    const int db   = (w & 1) * 32;   // d-block

    for (int it = 0; it < 4; ++it) {
        const int base = it * 128;
        // --- stage 128 rows row-major bf16 (no transpose) ---
#pragma unroll
        for (int rn = 0; rn < 4; ++rn) {
            const int nl = 4 * p_nq + rn;
            const float4 v = *(const float4*)&X[(base + nl) * DD + 4 * p_dq];
            bf16x4 h4;
            h4[0] = (bf16)v.x; h4[1] = (bf16)v.y; h4[2] = (bf16)v.z; h4[3] = (bf16)v.w;
            *(bf16x4*)&Xr[nl * 72 + 4 * p_dq] = h4;
        }
        __syncthreads();
        // --- compute: A = X rows (K=d), B = H via symmetry (row reads) ---
        f32x16 o;
#pragma unroll
        for (int q = 0; q < 16; ++q) o[q] = 0.f;
#pragma unroll
        for (int ks = 0; ks < 4; ++ks) {
            bf16x8 a = *(const bf16x8*)&Xr [(nb + l31) * 72 + ks * 16 + 8 * l5];
            bf16x8 b = *(const bf16x8*)&Hbf[(db + l31) * 72 + ks * 16 + 8 * l5];
            o = __builtin_amdgcn_mfma_f32_32x32x16_bf16(a, b, o, 0, 0, 0);
        }
        // --- epilogue: out = X + X*H; 128B-contiguous dword stores ---
#pragma unroll
        for (int q = 0; q < 16; ++q) {
            const int rl = (q & 3) + 8 * (q >> 2) + 4 * l5;
            const int nl = nb + rl;
            const int d  = db + l31;
            O[(size_t)(base + nl) * DD + d] = o[q] + (float)Xr[nl * 72 + d];
        }
        __syncthreads();
    }
}

}  // namespace

extern "C" void kernel_launch(void* const* d_in, const int* in_sizes, int n_in,
                              void* d_out, int out_size, void* d_ws, size_t ws_size,
                              hipStream_t stream) {
    const float* inp = (const float*)d_in[0];
    const float* aw  = (const float*)d_in[1];
    const float* bw  = (const float*)d_in[2];
    float* out       = (float*)d_out;

    ns_mfma<<<dim3(512), dim3(512), 0, stream>>>(inp, aw, bw, out);
}

// Round 3
// 25.623 us; speedup vs baseline: 3.4719x; 1.3548x over previous
//
#include <hip/hip_runtime.h>

// NSLayer: out = X + (-a*(X X^T) + b*(X X^T)^2) X per (b,c) slice, X: [512][64].
// Factored: G = X^T X (64x64), H = -a*G + b*G^2 (symmetric), out = X + X*H.
// bf16 MFMA (32x32x16) for all three matmuls, fp32 accumulate.
// Round 3: X loaded ONCE into regs up-front (16 float4/thread, max MLP);
// pass1 and pass3 stage LDS from regs; Gp1 dropped via sequential reduce.
// 512 blocks x 512 threads (8 waves). LDS 53 KiB.

typedef __bf16 bf16;
typedef __attribute__((ext_vector_type(8)))  __bf16 bf16x8;
typedef __attribute__((ext_vector_type(4)))  __bf16 bf16x4;
typedef __attribute__((ext_vector_type(16))) float  f32x16;

namespace {

constexpr int DD = 64;

__device__ __forceinline__ int sxz(int d) { return ((d >> 1) ^ (d >> 4)) & 7; }

__global__ __launch_bounds__(512, 4)
void ns_mfma(const float* __restrict__ inp, const float* __restrict__ aw,
             const float* __restrict__ bw, float* __restrict__ out) {
    // LDS map (54272 B total):
    //   [0,18432):      pass1: Xt0[64][72]bf16 + Xt1[64][72]bf16
    //                   pass3: Xr[128][72]bf16 (overlay)
    //   [18432,35840):  Gp[64][68]f32 partial (half-0's G)
    //   [35840,45056):  Gbf[64][72]bf16
    //   [45056,54272):  Hbf[64][72]bf16
    __shared__ unsigned char smem[54272] __attribute__((aligned(128)));
    bf16*  const Xt0 = (bf16*)smem;
    bf16*  const Xt1 = (bf16*)(smem + 9216);
    bf16*  const Xr  = (bf16*)smem;
    float* const Gp  = (float*)(smem + 18432);
    bf16*  const Gbf = (bf16*)(smem + 35840);
    bf16*  const Hbf = (bf16*)(smem + 45056);

    const int slice = blockIdx.x;                // b*64 + c
    const float av = aw[slice & 63];
    const float bv = bw[slice & 63];
    const float* __restrict__ X = inp + (size_t)slice * (512 * DD);
    float* __restrict__ O       = out + (size_t)slice * (512 * DD);

    const int t    = threadIdx.x;
    const int lane = t & 63;
    const int w    = t >> 6;       // wave 0..7
    const int l31  = lane & 31;
    const int l5   = lane >> 5;    // 0/1
    const int half = t >> 8;       // == w>>2
    const int th   = t & 255;
    const int s_nq = th >> 4;      // 0..15
    const int s_dq = th & 15;      // 0..15

    // ====== Load entire X share into regs (once), convert to bf16 ==========
    // xr[s][rn] holds rows (256*half + 64*s + 4*s_nq + rn), cols 4*s_dq..+4
    bf16x4 xr[4][4];
    {
        float4 rv[4][4];
#pragma unroll
        for (int s = 0; s < 4; ++s)
#pragma unroll
            for (int rn = 0; rn < 4; ++rn)
                rv[s][rn] = *(const float4*)&X[(256 * half + 64 * s + 4 * s_nq + rn) * DD + 4 * s_dq];
#pragma unroll
        for (int s = 0; s < 4; ++s)
#pragma unroll
            for (int rn = 0; rn < 4; ++rn) {
                xr[s][rn][0] = (bf16)rv[s][rn].x;
                xr[s][rn][1] = (bf16)rv[s][rn].y;
                xr[s][rn][2] = (bf16)rv[s][rn].z;
                xr[s][rn][3] = (bf16)rv[s][rn].w;
            }
    }

    // ================= Pass 1: G = X^T X, K-split across halves ============
    f32x16 acc;
#pragma unroll
    for (int q = 0; q < 16; ++q) acc[q] = 0.f;

    bf16* const XtMine = half ? Xt1 : Xt0;
    const int tile = w & 3;
    const int i32  = (tile >> 1) * 32;
    const int j32  = (tile & 1) * 32;
    const int rowA = i32 + l31;
    const int rowB = j32 + l31;
    const int sA   = sxz(rowA);
    const int sB   = sxz(rowB);

    for (int it = 0; it < 4; ++it) {
        // --- stage chunk (4*half + it) transposed, from regs ---
#pragma unroll
        for (int r = 0; r < 4; ++r) {
            const int d = 4 * s_dq + r;
            bf16x4 v;
            v[0] = xr[it][0][r]; v[1] = xr[it][1][r];
            v[2] = xr[it][2][r]; v[3] = xr[it][3][r];
            const int g = ((s_nq >> 1) ^ sxz(d)) & 7;   // 16B-granule swizzle
            *(bf16x4*)&XtMine[d * 72 + g * 8 + 4 * (s_nq & 1)] = v;
        }
        __syncthreads();
        // --- 4 K-steps (K=16 each) over this 64-n chunk ---
#pragma unroll
        for (int ks = 0; ks < 4; ++ks) {
            const int gw = 2 * ks + l5;
            bf16x8 a = *(const bf16x8*)&XtMine[rowA * 72 + ((gw ^ sA) & 7) * 8];
            bf16x8 b = *(const bf16x8*)&XtMine[rowB * 72 + ((gw ^ sB) & 7) * 8];
            acc = __builtin_amdgcn_mfma_f32_32x32x16_bf16(a, b, acc, 0, 0, 0);
        }
        __syncthreads();
    }

    // ====== Sequential G reduce: half0 -> Gp (f32); half1 adds -> Gbf ======
    if (half == 0) {
#pragma unroll
        for (int q = 0; q < 16; ++q) {
            const int r = (q & 3) + 8 * (q >> 2) + 4 * l5;   // C/D row (m74/m101)
            Gp[(i32 + r) * 68 + j32 + l31] = acc[q];
        }
    }
    __syncthreads();
    if (half == 1) {
#pragma unroll
        for (int q = 0; q < 16; ++q) {
            const int r  = (q & 3) + 8 * (q >> 2) + 4 * l5;
            const int ii = i32 + r;
            const int jj = j32 + l31;
            Gbf[ii * 72 + jj] = (bf16)(acc[q] + Gp[ii * 68 + jj]);
        }
    }
    __syncthreads();

    // ================= Pass 2: H = b*G^2 - a*G (waves 0-3) =================
    if (w < 4) {
        const int pi = (w >> 1) * 32;
        const int pj = (w & 1) * 32;
        f32x16 h;
#pragma unroll
        for (int q = 0; q < 16; ++q) h[q] = 0.f;
#pragma unroll
        for (int ks = 0; ks < 4; ++ks) {
            // G symmetric: both operands are row reads of Gbf
            bf16x8 a = *(const bf16x8*)&Gbf[(pi + l31) * 72 + ks * 16 + 8 * l5];
            bf16x8 b = *(const bf16x8*)&Gbf[(pj + l31) * 72 + ks * 16 + 8 * l5];
            h = __builtin_amdgcn_mfma_f32_32x32x16_bf16(a, b, h, 0, 0, 0);
        }
#pragma unroll
        for (int q = 0; q < 16; ++q) {
            const int r  = (q & 3) + 8 * (q >> 2) + 4 * l5;
            const int ii = pi + r;
            const int jj = pj + l31;
            Hbf[ii * 72 + jj] = (bf16)(bv * h[q] - av * (float)Gbf[ii * 72 + jj]);
        }
    }
    __syncthreads();

    // ================= Pass 3: out = X + X*H (staged from regs) ============
    const int nb = (w >> 1) * 32;   // n-block within 128-row chunk
    const int db = (w & 1) * 32;    // d-block

    for (int it = 0; it < 4; ++it) {
        // --- stage 128 rows row-major bf16 from regs (active half only) ---
        if (half == (it >> 1)) {
#pragma unroll
            for (int ss = 0; ss < 2; ++ss) {
                const int s   = 2 * (it & 1) + ss;
                const int nlb = 64 * ss + 4 * s_nq;
#pragma unroll
                for (int rn = 0; rn < 4; ++rn)
                    *(bf16x4*)&Xr[(nlb + rn) * 72 + 4 * s_dq] = xr[s][rn];
            }
        }
        __syncthreads();

        // --- A = X rows (K=d), B = H via symmetry (row reads) ---
        f32x16 o;
#pragma unroll
        for (int q = 0; q < 16; ++q) o[q] = 0.f;
#pragma unroll
        for (int ks = 0; ks < 4; ++ks) {
            bf16x8 a = *(const bf16x8*)&Xr [(nb + l31) * 72 + ks * 16 + 8 * l5];
            bf16x8 b = *(const bf16x8*)&Hbf[(db + l31) * 72 + ks * 16 + 8 * l5];
            o = __builtin_amdgcn_mfma_f32_32x32x16_bf16(a, b, o, 0, 0, 0);
        }

        // --- epilogue: out = X + X*H; 128B-contiguous dword stores ---
#pragma unroll
        for (int q = 0; q < 16; ++q) {
            const int rl = (q & 3) + 8 * (q >> 2) + 4 * l5;
            const int nl = nb + rl;
            const int d  = db + l31;
            O[(size_t)(it * 128 + nl) * DD + d] = o[q] + (float)Xr[nl * 72 + d];
        }
        __syncthreads();
    }
}

}  // namespace

extern "C" void kernel_launch(void* const* d_in, const int* in_sizes, int n_in,
                              void* d_out, int out_size, void* d_ws, size_t ws_size,
                              hipStream_t stream) {
    const float* inp = (const float*)d_in[0];
    const float* aw  = (const float*)d_in[1];
    const float* bw  = (const float*)d_in[2];
    float* out       = (float*)d_out;

    ns_mfma<<<dim3(512), dim3(512), 0, stream>>>(inp, aw, bw, out);
}

// Round 4
// 25.606 us; speedup vs baseline: 3.4743x; 1.0007x over previous
//
#include <hip/hip_runtime.h>

// NSLayer: out = X + (-a*(X X^T) + b*(X X^T)^2) X per (b,c) slice, X: [512][64].
// Factored: G = X^T X (64x64), H = -a*G + b*G^2 (symmetric), out = X + X*H.
// bf16 MFMA (32x32x16) for all three matmuls, fp32 accumulate.
// Round 3: X loaded ONCE into regs up-front (16 float4/thread, max MLP);
// pass1 and pass3 stage LDS from regs; Gp1 dropped via sequential reduce.
// 512 blocks x 512 threads (8 waves). LDS 53 KiB.

typedef __bf16 bf16;
typedef __attribute__((ext_vector_type(8)))  __bf16 bf16x8;
typedef __attribute__((ext_vector_type(4)))  __bf16 bf16x4;
typedef __attribute__((ext_vector_type(16))) float  f32x16;

namespace {

constexpr int DD = 64;

__device__ __forceinline__ int sxz(int d) { return ((d >> 1) ^ (d >> 4)) & 7; }

__global__ __launch_bounds__(512, 4)
void ns_mfma(const float* __restrict__ inp, const float* __restrict__ aw,
             const float* __restrict__ bw, float* __restrict__ out) {
    // LDS map (54272 B total):
    //   [0,18432):      pass1: Xt0[64][72]bf16 + Xt1[64][72]bf16
    //                   pass3: Xr[128][72]bf16 (overlay)
    //   [18432,35840):  Gp[64][68]f32 partial (half-0's G)
    //   [35840,45056):  Gbf[64][72]bf16
    //   [45056,54272):  Hbf[64][72]bf16
    __shared__ unsigned char smem[54272] __attribute__((aligned(128)));
    bf16*  const Xt0 = (bf16*)smem;
    bf16*  const Xt1 = (bf16*)(smem + 9216);
    bf16*  const Xr  = (bf16*)smem;
    float* const Gp  = (float*)(smem + 18432);
    bf16*  const Gbf = (bf16*)(smem + 35840);
    bf16*  const Hbf = (bf16*)(smem + 45056);

    const int slice = blockIdx.x;                // b*64 + c
    const float av = aw[slice & 63];
    const float bv = bw[slice & 63];
    const float* __restrict__ X = inp + (size_t)slice * (512 * DD);
    float* __restrict__ O       = out + (size_t)slice * (512 * DD);

    const int t    = threadIdx.x;
    const int lane = t & 63;
    const int w    = t >> 6;       // wave 0..7
    const int l31  = lane & 31;
    const int l5   = lane >> 5;    // 0/1
    const int half = t >> 8;       // == w>>2
    const int th   = t & 255;
    const int s_nq = th >> 4;      // 0..15
    const int s_dq = th & 15;      // 0..15

    // ====== Load entire X share into regs (once), convert to bf16 ==========
    // xr[s][rn] holds rows (256*half + 64*s + 4*s_nq + rn), cols 4*s_dq..+4
    bf16x4 xr[4][4];
    {
        float4 rv[4][4];
#pragma unroll
        for (int s = 0; s < 4; ++s)
#pragma unroll
            for (int rn = 0; rn < 4; ++rn)
                rv[s][rn] = *(const float4*)&X[(256 * half + 64 * s + 4 * s_nq + rn) * DD + 4 * s_dq];
#pragma unroll
        for (int s = 0; s < 4; ++s)
#pragma unroll
            for (int rn = 0; rn < 4; ++rn) {
                xr[s][rn][0] = (bf16)rv[s][rn].x;
                xr[s][rn][1] = (bf16)rv[s][rn].y;
                xr[s][rn][2] = (bf16)rv[s][rn].z;
                xr[s][rn][3] = (bf16)rv[s][rn].w;
            }
    }

    // ================= Pass 1: G = X^T X, K-split across halves ============
    f32x16 acc;
#pragma unroll
    for (int q = 0; q < 16; ++q) acc[q] = 0.f;

    bf16* const XtMine = half ? Xt1 : Xt0;
    const int tile = w & 3;
    const int i32  = (tile >> 1) * 32;
    const int j32  = (tile & 1) * 32;
    const int rowA = i32 + l31;
    const int rowB = j32 + l31;
    const int sA   = sxz(rowA);
    const int sB   = sxz(rowB);

    for (int it = 0; it < 4; ++it) {
        // --- stage chunk (4*half + it) transposed, from regs ---
#pragma unroll
        for (int r = 0; r < 4; ++r) {
            const int d = 4 * s_dq + r;
            bf16x4 v;
            v[0] = xr[it][0][r]; v[1] = xr[it][1][r];
            v[2] = xr[it][2][r]; v[3] = xr[it][3][r];
            const int g = ((s_nq >> 1) ^ sxz(d)) & 7;   // 16B-granule swizzle
            *(bf16x4*)&XtMine[d * 72 + g * 8 + 4 * (s_nq & 1)] = v;
        }
        __syncthreads();
        // --- 4 K-steps (K=16 each) over this 64-n chunk ---
#pragma unroll
        for (int ks = 0; ks < 4; ++ks) {
            const int gw = 2 * ks + l5;
            bf16x8 a = *(const bf16x8*)&XtMine[rowA * 72 + ((gw ^ sA) & 7) * 8];
            bf16x8 b = *(const bf16x8*)&XtMine[rowB * 72 + ((gw ^ sB) & 7) * 8];
            acc = __builtin_amdgcn_mfma_f32_32x32x16_bf16(a, b, acc, 0, 0, 0);
        }
        __syncthreads();
    }

    // ====== Sequential G reduce: half0 -> Gp (f32); half1 adds -> Gbf ======
    if (half == 0) {
#pragma unroll
        for (int q = 0; q < 16; ++q) {
            const int r = (q & 3) + 8 * (q >> 2) + 4 * l5;   // C/D row (m74/m101)
            Gp[(i32 + r) * 68 + j32 + l31] = acc[q];
        }
    }
    __syncthreads();
    if (half == 1) {
#pragma unroll
        for (int q = 0; q < 16; ++q) {
            const int r  = (q & 3) + 8 * (q >> 2) + 4 * l5;
            const int ii = i32 + r;
            const int jj = j32 + l31;
            Gbf[ii * 72 + jj] = (bf16)(acc[q] + Gp[ii * 68 + jj]);
        }
    }
    __syncthreads();

    // ================= Pass 2: H = b*G^2 - a*G (waves 0-3) =================
    if (w < 4) {
        const int pi = (w >> 1) * 32;
        const int pj = (w & 1) * 32;
        f32x16 h;
#pragma unroll
        for (int q = 0; q < 16; ++q) h[q] = 0.f;
#pragma unroll
        for (int ks = 0; ks < 4; ++ks) {
            // G symmetric: both operands are row reads of Gbf
            bf16x8 a = *(const bf16x8*)&Gbf[(pi + l31) * 72 + ks * 16 + 8 * l5];
            bf16x8 b = *(const bf16x8*)&Gbf[(pj + l31) * 72 + ks * 16 + 8 * l5];
            h = __builtin_amdgcn_mfma_f32_32x32x16_bf16(a, b, h, 0, 0, 0);
        }
#pragma unroll
        for (int q = 0; q < 16; ++q) {
            const int r  = (q & 3) + 8 * (q >> 2) + 4 * l5;
            const int ii = pi + r;
            const int jj = pj + l31;
            Hbf[ii * 72 + jj] = (bf16)(bv * h[q] - av * (float)Gbf[ii * 72 + jj]);
        }
    }
    __syncthreads();

    // ================= Pass 3: out = X + X*H (staged from regs) ============
    const int nb = (w >> 1) * 32;   // n-block within 128-row chunk
    const int db = (w & 1) * 32;    // d-block

    for (int it = 0; it < 4; ++it) {
        // --- stage 128 rows row-major bf16 from regs (active half only) ---
        if (half == (it >> 1)) {
#pragma unroll
            for (int ss = 0; ss < 2; ++ss) {
                const int s   = 2 * (it & 1) + ss;
                const int nlb = 64 * ss + 4 * s_nq;
#pragma unroll
                for (int rn = 0; rn < 4; ++rn)
                    *(bf16x4*)&Xr[(nlb + rn) * 72 + 4 * s_dq] = xr[s][rn];
            }
        }
        __syncthreads();

        // --- A = X rows (K=d), B = H via symmetry (row reads) ---
        f32x16 o;
#pragma unroll
        for (int q = 0; q < 16; ++q) o[q] = 0.f;
#pragma unroll
        for (int ks = 0; ks < 4; ++ks) {
            bf16x8 a = *(const bf16x8*)&Xr [(nb + l31) * 72 + ks * 16 + 8 * l5];
            bf16x8 b = *(const bf16x8*)&Hbf[(db + l31) * 72 + ks * 16 + 8 * l5];
            o = __builtin_amdgcn_mfma_f32_32x32x16_bf16(a, b, o, 0, 0, 0);
        }

        // --- epilogue: out = X + X*H; 128B-contiguous dword stores ---
#pragma unroll
        for (int q = 0; q < 16; ++q) {
            const int rl = (q & 3) + 8 * (q >> 2) + 4 * l5;
            const int nl = nb + rl;
            const int d  = db + l31;
            O[(size_t)(it * 128 + nl) * DD + d] = o[q] + (float)Xr[nl * 72 + d];
        }
        __syncthreads();
    }
}

}  // namespace

extern "C" void kernel_launch(void* const* d_in, const int* in_sizes, int n_in,
                              void* d_out, int out_size, void* d_ws, size_t ws_size,
                              hipStream_t stream) {
    const float* inp = (const float*)d_in[0];
    const float* aw  = (const float*)d_in[1];
    const float* bw  = (const float*)d_in[2];
    float* out       = (float*)d_out;

    ns_mfma<<<dim3(512), dim3(512), 0, stream>>>(inp, aw, bw, out);
}

// Round 5
// 25.494 us; speedup vs baseline: 3.4895x; 1.0044x over previous
//
#include <hip/hip_runtime.h>

// NSLayer: out = X + (-a*(X X^T) + b*(X X^T)^2) X per (b,c) slice, X: [512][64].
// Factored: G = X^T X (64x64), H = -a*G + b*G^2 (symmetric), out = X + X*H.
// bf16 MFMA (32x32x16) for all three matmuls, fp32 accumulate.
// Round 3: X loaded ONCE into regs up-front (16 float4/thread, max MLP);
// pass1 and pass3 stage LDS from regs; Gp1 dropped via sequential reduce.
// 512 blocks x 512 threads (8 waves). LDS 53 KiB.

typedef __bf16 bf16;
typedef __attribute__((ext_vector_type(8)))  __bf16 bf16x8;
typedef __attribute__((ext_vector_type(4)))  __bf16 bf16x4;
typedef __attribute__((ext_vector_type(16))) float  f32x16;

namespace {

constexpr int DD = 64;

__device__ __forceinline__ int sxz(int d) { return ((d >> 1) ^ (d >> 4)) & 7; }

__global__ __launch_bounds__(512, 4)
void ns_mfma(const float* __restrict__ inp, const float* __restrict__ aw,
             const float* __restrict__ bw, float* __restrict__ out) {
    // LDS map (54272 B total):
    //   [0,18432):      pass1: Xt0[64][72]bf16 + Xt1[64][72]bf16
    //                   pass3: Xr[128][72]bf16 (overlay)
    //   [18432,35840):  Gp[64][68]f32 partial (half-0's G)
    //   [35840,45056):  Gbf[64][72]bf16
    //   [45056,54272):  Hbf[64][72]bf16
    __shared__ unsigned char smem[54272] __attribute__((aligned(128)));
    bf16*  const Xt0 = (bf16*)smem;
    bf16*  const Xt1 = (bf16*)(smem + 9216);
    bf16*  const Xr  = (bf16*)smem;
    float* const Gp  = (float*)(smem + 18432);
    bf16*  const Gbf = (bf16*)(smem + 35840);
    bf16*  const Hbf = (bf16*)(smem + 45056);

    const int slice = blockIdx.x;                // b*64 + c
    const float av = aw[slice & 63];
    const float bv = bw[slice & 63];
    const float* __restrict__ X = inp + (size_t)slice * (512 * DD);
    float* __restrict__ O       = out + (size_t)slice * (512 * DD);

    const int t    = threadIdx.x;
    const int lane = t & 63;
    const int w    = t >> 6;       // wave 0..7
    const int l31  = lane & 31;
    const int l5   = lane >> 5;    // 0/1
    const int half = t >> 8;       // == w>>2
    const int th   = t & 255;
    const int s_nq = th >> 4;      // 0..15
    const int s_dq = th & 15;      // 0..15

    // ====== Load entire X share into regs (once), convert to bf16 ==========
    // xr[s][rn] holds rows (256*half + 64*s + 4*s_nq + rn), cols 4*s_dq..+4
    bf16x4 xr[4][4];
    {
        float4 rv[4][4];
#pragma unroll
        for (int s = 0; s < 4; ++s)
#pragma unroll
            for (int rn = 0; rn < 4; ++rn)
                rv[s][rn] = *(const float4*)&X[(256 * half + 64 * s + 4 * s_nq + rn) * DD + 4 * s_dq];
#pragma unroll
        for (int s = 0; s < 4; ++s)
#pragma unroll
            for (int rn = 0; rn < 4; ++rn) {
                xr[s][rn][0] = (bf16)rv[s][rn].x;
                xr[s][rn][1] = (bf16)rv[s][rn].y;
                xr[s][rn][2] = (bf16)rv[s][rn].z;
                xr[s][rn][3] = (bf16)rv[s][rn].w;
            }
    }

    // ================= Pass 1: G = X^T X, K-split across halves ============
    f32x16 acc;
#pragma unroll
    for (int q = 0; q < 16; ++q) acc[q] = 0.f;

    bf16* const XtMine = half ? Xt1 : Xt0;
    const int tile = w & 3;
    const int i32  = (tile >> 1) * 32;
    const int j32  = (tile & 1) * 32;
    const int rowA = i32 + l31;
    const int rowB = j32 + l31;
    const int sA   = sxz(rowA);
    const int sB   = sxz(rowB);

    for (int it = 0; it < 4; ++it) {
        // --- stage chunk (4*half + it) transposed, from regs ---
#pragma unroll
        for (int r = 0; r < 4; ++r) {
            const int d = 4 * s_dq + r;
            bf16x4 v;
            v[0] = xr[it][0][r]; v[1] = xr[it][1][r];
            v[2] = xr[it][2][r]; v[3] = xr[it][3][r];
            const int g = ((s_nq >> 1) ^ sxz(d)) & 7;   // 16B-granule swizzle
            *(bf16x4*)&XtMine[d * 72 + g * 8 + 4 * (s_nq & 1)] = v;
        }
        __syncthreads();
        // --- 4 K-steps (K=16 each) over this 64-n chunk ---
#pragma unroll
        for (int ks = 0; ks < 4; ++ks) {
            const int gw = 2 * ks + l5;
            bf16x8 a = *(const bf16x8*)&XtMine[rowA * 72 + ((gw ^ sA) & 7) * 8];
            bf16x8 b = *(const bf16x8*)&XtMine[rowB * 72 + ((gw ^ sB) & 7) * 8];
            acc = __builtin_amdgcn_mfma_f32_32x32x16_bf16(a, b, acc, 0, 0, 0);
        }
        __syncthreads();
    }

    // ====== Sequential G reduce: half0 -> Gp (f32); half1 adds -> Gbf ======
    if (half == 0) {
#pragma unroll
        for (int q = 0; q < 16; ++q) {
            const int r = (q & 3) + 8 * (q >> 2) + 4 * l5;   // C/D row (m74/m101)
            Gp[(i32 + r) * 68 + j32 + l31] = acc[q];
        }
    }
    __syncthreads();
    if (half == 1) {
#pragma unroll
        for (int q = 0; q < 16; ++q) {
            const int r  = (q & 3) + 8 * (q >> 2) + 4 * l5;
            const int ii = i32 + r;
            const int jj = j32 + l31;
            Gbf[ii * 72 + jj] = (bf16)(acc[q] + Gp[ii * 68 + jj]);
        }
    }
    __syncthreads();

    // ================= Pass 2: H = b*G^2 - a*G (waves 0-3) =================
    if (w < 4) {
        const int pi = (w >> 1) * 32;
        const int pj = (w & 1) * 32;
        f32x16 h;
#pragma unroll
        for (int q = 0; q < 16; ++q) h[q] = 0.f;
#pragma unroll
        for (int ks = 0; ks < 4; ++ks) {
            // G symmetric: both operands are row reads of Gbf
            bf16x8 a = *(const bf16x8*)&Gbf[(pi + l31) * 72 + ks * 16 + 8 * l5];
            bf16x8 b = *(const bf16x8*)&Gbf[(pj + l31) * 72 + ks * 16 + 8 * l5];
            h = __builtin_amdgcn_mfma_f32_32x32x16_bf16(a, b, h, 0, 0, 0);
        }
#pragma unroll
        for (int q = 0; q < 16; ++q) {
            const int r  = (q & 3) + 8 * (q >> 2) + 4 * l5;
            const int ii = pi + r;
            const int jj = pj + l31;
            Hbf[ii * 72 + jj] = (bf16)(bv * h[q] - av * (float)Gbf[ii * 72 + jj]);
        }
    }
    __syncthreads();

    // ================= Pass 3: out = X + X*H (staged from regs) ============
    const int nb = (w >> 1) * 32;   // n-block within 128-row chunk
    const int db = (w & 1) * 32;    // d-block

    for (int it = 0; it < 4; ++it) {
        // --- stage 128 rows row-major bf16 from regs (active half only) ---
        if (half == (it >> 1)) {
#pragma unroll
            for (int ss = 0; ss < 2; ++ss) {
                const int s   = 2 * (it & 1) + ss;
                const int nlb = 64 * ss + 4 * s_nq;
#pragma unroll
                for (int rn = 0; rn < 4; ++rn)
                    *(bf16x4*)&Xr[(nlb + rn) * 72 + 4 * s_dq] = xr[s][rn];
            }
        }
        __syncthreads();

        // --- A = X rows (K=d), B = H via symmetry (row reads) ---
        f32x16 o;
#pragma unroll
        for (int q = 0; q < 16; ++q) o[q] = 0.f;
#pragma unroll
        for (int ks = 0; ks < 4; ++ks) {
            bf16x8 a = *(const bf16x8*)&Xr [(nb + l31) * 72 + ks * 16 + 8 * l5];
            bf16x8 b = *(const bf16x8*)&Hbf[(db + l31) * 72 + ks * 16 + 8 * l5];
            o = __builtin_amdgcn_mfma_f32_32x32x16_bf16(a, b, o, 0, 0, 0);
        }

        // --- epilogue: out = X + X*H; 128B-contiguous dword stores ---
#pragma unroll
        for (int q = 0; q < 16; ++q) {
            const int rl = (q & 3) + 8 * (q >> 2) + 4 * l5;
            const int nl = nb + rl;
            const int d  = db + l31;
            O[(size_t)(it * 128 + nl) * DD + d] = o[q] + (float)Xr[nl * 72 + d];
        }
        __syncthreads();
    }
}

}  // namespace

extern "C" void kernel_launch(void* const* d_in, const int* in_sizes, int n_in,
                              void* d_out, int out_size, void* d_ws, size_t ws_size,
                              hipStream_t stream) {
    const float* inp = (const float*)d_in[0];
    const float* aw  = (const float*)d_in[1];
    const float* bw  = (const float*)d_in[2];
    float* out       = (float*)d_out;

    ns_mfma<<<dim3(512), dim3(512), 0, stream>>>(inp, aw, bw, out);
}